// Round 1
// baseline (847.287 us; speedup 1.0000x reference)
//
#include <hip/hip_runtime.h>
#include <stdint.h>

#define DF 128

// ---------------- Threefry-2x32 (JAX-compatible, 20 rounds) ----------------
__host__ __device__ __forceinline__ unsigned rotl32(unsigned v, int r) {
  return (v << r) | (v >> (32 - r));
}

__host__ __device__ __forceinline__ void threefry2x32(
    unsigned k0, unsigned k1, unsigned c0, unsigned c1,
    unsigned& o0, unsigned& o1) {
  unsigned kx = k0 ^ k1 ^ 0x1BD11BDAu;
  unsigned x0 = c0 + k0;
  unsigned x1 = c1 + k1;
#define TF_R(r) { x0 += x1; x1 = rotl32(x1, r); x1 ^= x0; }
  TF_R(13) TF_R(15) TF_R(26) TF_R(6)
  x0 += k1; x1 += kx + 1u;
  TF_R(17) TF_R(29) TF_R(16) TF_R(24)
  x0 += kx; x1 += k0 + 2u;
  TF_R(13) TF_R(15) TF_R(26) TF_R(6)
  x0 += k0; x1 += k1 + 3u;
  TF_R(17) TF_R(29) TF_R(16) TF_R(24)
  x0 += k1; x1 += kx + 4u;
  TF_R(13) TF_R(15) TF_R(26) TF_R(6)
  x0 += kx; x1 += k0 + 5u;
#undef TF_R
  o0 = x0; o1 = x1;
}

// keep iff uniform(bits) < 0.9f  <=>  (bits>>9) < 0x733333  <=>  bits < 0xE6666600
#define KEEP_THR 0xE6666600u

// ---------------- GEMM [nrows,128] x [128,128] with fused epilogue ----------
// EPI 0: out = X@W
// EPI 1: out = relu(X@W + acc1/max(cnt1,1))
// EPI 2: out = relu(0.5*(X@W + acc1/max(cnt1,1) + acc2/max(cnt2,1)))
template <int EPI>
__global__ __launch_bounds__(256) void gemm128_epi(
    const float* __restrict__ X, const float* __restrict__ W,
    int nrows, float* __restrict__ out,
    const float* __restrict__ acc1, const unsigned* __restrict__ cnt1,
    const float* __restrict__ acc2, const unsigned* __restrict__ cnt2) {
  __shared__ float Wl[32][DF];                 // K-tile of W
  __shared__ __align__(16) float Xt[32][68];   // transposed x tile [k][row], padded
  const int t = threadIdx.x;
  const int rbase = blockIdx.x * 64;
  const int c4 = (t & 31) * 4;     // 4 output cols
  const int r0 = (t >> 5) * 8;     // 8 output rows
  float acc[8][4];
#pragma unroll
  for (int i = 0; i < 8; ++i)
#pragma unroll
    for (int j = 0; j < 4; ++j) acc[i][j] = 0.f;

  for (int kt = 0; kt < 4; ++kt) {
    const int k0 = kt * 32;
    if (kt) __syncthreads();
    // stage W k-tile: 1024 float4, 4 per thread (coalesced)
#pragma unroll
    for (int i = 0; i < 4; ++i) {
      int u = t + i * 256;
      int kk = u >> 5;
      int cc = (u & 31) * 4;
      *reinterpret_cast<float4*>(&Wl[kk][cc]) =
          *reinterpret_cast<const float4*>(&W[(k0 + kk) * DF + cc]);
    }
    // stage X k-tile transposed: 512 float4 loads, scalar LDS writes
#pragma unroll
    for (int i = 0; i < 2; ++i) {
      int u = t + i * 256;
      int r = u >> 3;
      int kk4 = (u & 7) * 4;
      int gr = rbase + r;
      float4 x = make_float4(0.f, 0.f, 0.f, 0.f);
      if (gr < nrows)
        x = *reinterpret_cast<const float4*>(&X[(size_t)gr * DF + k0 + kk4]);
      Xt[kk4 + 0][r] = x.x;
      Xt[kk4 + 1][r] = x.y;
      Xt[kk4 + 2][r] = x.z;
      Xt[kk4 + 3][r] = x.w;
    }
    __syncthreads();
#pragma unroll
    for (int k = 0; k < 32; ++k) {
      float4 w = *reinterpret_cast<const float4*>(&Wl[k][c4]);
      float4 xa = *reinterpret_cast<const float4*>(&Xt[k][r0]);
      float4 xb = *reinterpret_cast<const float4*>(&Xt[k][r0 + 4]);
      float ws4[4] = {w.x, w.y, w.z, w.w};
      float xs8[8] = {xa.x, xa.y, xa.z, xa.w, xb.x, xb.y, xb.z, xb.w};
#pragma unroll
      for (int i = 0; i < 8; ++i)
#pragma unroll
        for (int j = 0; j < 4; ++j)
          acc[i][j] = fmaf(xs8[i], ws4[j], acc[i][j]);
    }
  }

#pragma unroll
  for (int i = 0; i < 8; ++i) {
    int r = rbase + r0 + i;
    if (r < nrows) {
      float4 v;
      if (EPI == 0) {
        v = make_float4(acc[i][0], acc[i][1], acc[i][2], acc[i][3]);
      } else if (EPI == 1) {
        float n1 = fmaxf((float)cnt1[r], 1.0f);
        float4 a1 = *reinterpret_cast<const float4*>(&acc1[(size_t)r * DF + c4]);
        v.x = fmaxf(acc[i][0] + a1.x / n1, 0.f);
        v.y = fmaxf(acc[i][1] + a1.y / n1, 0.f);
        v.z = fmaxf(acc[i][2] + a1.z / n1, 0.f);
        v.w = fmaxf(acc[i][3] + a1.w / n1, 0.f);
      } else {
        float n1 = fmaxf((float)cnt1[r], 1.0f);
        float n2 = fmaxf((float)cnt2[r], 1.0f);
        float4 a1 = *reinterpret_cast<const float4*>(&acc1[(size_t)r * DF + c4]);
        float4 a2 = *reinterpret_cast<const float4*>(&acc2[(size_t)r * DF + c4]);
        v.x = fmaxf(0.5f * (acc[i][0] + a1.x / n1 + a2.x / n2), 0.f);
        v.y = fmaxf(0.5f * (acc[i][1] + a1.y / n1 + a2.y / n2), 0.f);
        v.z = fmaxf(0.5f * (acc[i][2] + a1.z / n1 + a2.z / n2), 0.f);
        v.w = fmaxf(0.5f * (acc[i][3] + a1.w / n1 + a2.w / n2), 0.f);
      }
      *reinterpret_cast<float4*>(&out[(size_t)r * DF + c4]) = v;
    }
  }
}

// ------------- per-edge: gather src proj, dropout (threefry), scatter-add ----
// Partitionable-threefry semantics: bits(l) = o0 ^ o1 of threefry(key, (0, l)),
// l = e*128 + d (row-major over the (E,128) bernoulli shape).
__global__ __launch_bounds__(256) void scatter_dropout_add(
    const float* __restrict__ proj, const int* __restrict__ src,
    const int* __restrict__ dst, float* __restrict__ accum,
    unsigned* __restrict__ cnt, int E, unsigned k0, unsigned k1) {
  int t = threadIdx.x;
  int e = blockIdx.x * 2 + (t >> 7);
  if (e >= E) return;
  int d = t & 127;
  unsigned l = (unsigned)e * 128u + (unsigned)d;
  unsigned b0, b1;
  threefry2x32(k0, k1, 0u, l, b0, b1);
  unsigned bits = b0 ^ b1;
  int s = src[e];
  int dd = dst[e];
  if (d == 0) atomicAdd(&cnt[dd], 1u);
  if (bits < KEEP_THR) {
    float g = proj[(size_t)s * DF + d] * (1.0f / 0.9f);
    atomicAdd(&accum[(size_t)dd * DF + d], g);
  }
}

__global__ __launch_bounds__(256) void addW(const float* __restrict__ a,
                                            const float* __restrict__ b,
                                            float* __restrict__ o) {
  int i = blockIdx.x * 256 + threadIdx.x;
  o[i] = a[i] + b[i];
}

// ---------------------------------------------------------------------------
extern "C" void kernel_launch(void* const* d_in, const int* in_sizes, int n_in,
                              void* d_out, int out_size, void* d_ws, size_t ws_size,
                              hipStream_t stream) {
  const float* x_user      = (const float*)d_in[0];
  const float* x_spot      = (const float*)d_in[1];
  const float* W_visit_src = (const float*)d_in[2];
  const float* W_visit_tgt = (const float*)d_in[3];
  const float* W_rev_src   = (const float*)d_in[4];
  const float* W_rev_tgt   = (const float*)d_in[5];
  const float* W_near_src  = (const float*)d_in[6];
  const float* W_near_tgt  = (const float*)d_in[7];
  const int* visit_src = (const int*)d_in[8];
  const int* visit_dst = (const int*)d_in[9];
  const int* rev_src   = (const int*)d_in[10];
  const int* rev_dst   = (const int*)d_in[11];
  const int* near_src  = (const int*)d_in[12];
  const int* near_dst  = (const int*)d_in[13];

  const int n_user = in_sizes[0] / DF;
  const int n_spot = in_sizes[1] / DF;
  const int e_visit = in_sizes[8];
  const int e_rev   = in_sizes[10];
  const int e_near  = in_sizes[12];

  float* out_user = (float*)d_out;
  float* out_spot = out_user + (size_t)n_user * DF;

  // workspace layout (accum_u aliases proj_vs, accum_sn aliases proj_rs:
  // each proj is dead by the time its alias is zeroed, stream-ordered)
  char* ws = (char*)d_ws;
  size_t off = 0;
  auto alloc = [&](size_t bytes) -> void* {
    void* p = ws + off;
    off += (bytes + 255) & ~(size_t)255;
    return p;
  };
  float* proj_vs  = (float*)alloc((size_t)n_user * DF * 4);
  float* proj_rs  = (float*)alloc((size_t)n_spot * DF * 4);
  float* proj_ns  = (float*)alloc((size_t)n_spot * DF * 4);
  float* accum_sv = (float*)alloc((size_t)n_spot * DF * 4);
  unsigned* cnt_u  = (unsigned*)alloc((size_t)n_user * 4);
  unsigned* cnt_sv = (unsigned*)alloc((size_t)n_spot * 4);
  unsigned* cnt_sn = (unsigned*)alloc((size_t)n_spot * 4);
  float* W_sum = (float*)alloc((size_t)DF * DF * 4);
  float* accum_u  = proj_vs;
  float* accum_sn = proj_rs;

  // dropout keys: fold_in(key(1), t) == threefry((0,1), (0,t))
  unsigned kv0, kv1, kr0, kr1, kn0, kn1;
  threefry2x32(0u, 1u, 0u, 0u, kv0, kv1);
  threefry2x32(0u, 1u, 0u, 1u, kr0, kr1);
  threefry2x32(0u, 1u, 0u, 2u, kn0, kn1);

  // zero accum_sv + the three count arrays in one contiguous memset
  hipMemsetAsync(accum_sv, 0, (size_t)((char*)W_sum - (char*)accum_sv), stream);

  dim3 blk(256);
  int gb_user = (n_user + 63) / 64;
  int gb_spot = (n_spot + 63) / 64;

  // source-side projections
  gemm128_epi<0><<<gb_user, blk, 0, stream>>>(x_user, W_visit_src, n_user, proj_vs,
                                              nullptr, nullptr, nullptr, nullptr);
  gemm128_epi<0><<<gb_spot, blk, 0, stream>>>(x_spot, W_rev_src, n_spot, proj_rs,
                                              nullptr, nullptr, nullptr, nullptr);
  gemm128_epi<0><<<gb_spot, blk, 0, stream>>>(x_spot, W_near_src, n_spot, proj_ns,
                                              nullptr, nullptr, nullptr, nullptr);
  addW<<<64, blk, 0, stream>>>(W_visit_tgt, W_near_tgt, W_sum);

  // visit: user -> spot
  scatter_dropout_add<<<(e_visit + 1) / 2, blk, 0, stream>>>(
      proj_vs, visit_src, visit_dst, accum_sv, cnt_sv, e_visit, kv0, kv1);

  // rev: spot -> user (accum_u reuses proj_vs storage)
  hipMemsetAsync(accum_u, 0, (size_t)n_user * DF * 4, stream);
  scatter_dropout_add<<<(e_rev + 1) / 2, blk, 0, stream>>>(
      proj_rs, rev_src, rev_dst, accum_u, cnt_u, e_rev, kr0, kr1);

  // near: spot -> spot (accum_sn reuses proj_rs storage)
  hipMemsetAsync(accum_sn, 0, (size_t)n_spot * DF * 4, stream);
  scatter_dropout_add<<<(e_near + 1) / 2, blk, 0, stream>>>(
      proj_ns, near_src, near_dst, accum_sn, cnt_sn, e_near, kn0, kn1);

  // finalize: fused tgt-projection + mean + relu
  gemm128_epi<1><<<gb_user, blk, 0, stream>>>(x_user, W_rev_tgt, n_user, out_user,
                                              accum_u, cnt_u, nullptr, nullptr);
  gemm128_epi<2><<<gb_spot, blk, 0, stream>>>(x_spot, W_sum, n_spot, out_spot,
                                              accum_sv, cnt_sv, accum_sn, cnt_sn);
}